// Round 5
// baseline (49.729 us; speedup 1.0000x reference)
//
#include <hip/hip_runtime.h>
#include <hip/hip_bf16.h>

// LocalPPM: B=4, C=256, H=W=56, R=2 (5x5 -> K2=25), TOPK=10, TAU=0.1, EPS=1e-8
// out = x + gamma * sum_k softmax_top10(cos_sim(center, neighbor_k)/TAU) * neighbor_k
//
// Symmetry: dot(p, +o) == dot(p+o, -o); only 13 offsets k=0..12 computed
// (dy=-2,-1 full rows; dy=0, dx<=0); k_fused mirrors the rest.
//
// Grid shape: 16-px tiles x 32 channel-chunks (8 ch) = 512 thr, 784 blocks
// (3.06/CU, 6272 waves) for both kernels — balance + latency hiding.

#define PX 3136   // 56*56
#define CS 3136   // channel plane stride (H*W)

__global__ __launch_bounds__(512) void k_dot(const float* __restrict__ x,
                                             float* __restrict__ dot) {
    const int px = threadIdx.x & 15;
    const int ck = threadIdx.x >> 4;               // 0..31 channel chunk (8 ch)
    const int p  = blockIdx.x * 16 + px;
    const int b  = blockIdx.y;
    const int h  = p / 56;
    const int w  = p - h * 56;

    const bool vm2 = (h >= 2), vm1 = (h >= 1);
    const bool cv0 = (w >= 2), cv1 = (w >= 1), cv3 = (w <= 54), cv4 = (w <= 53);

    const float* xb  = x + (size_t)b * 256 * CS + (size_t)ck * 8 * CS;
    const float* cp  = xb + p;        // center (row h, col w)
    const float* pr2 = cp - 112;      // row h-2
    const float* pr1 = cp - 56;       // row h-1

    float a[13];
    #pragma unroll
    for (int i = 0; i < 13; ++i) a[i] = 0.f;

    #pragma unroll
    for (int c = 0; c < 8; ++c) {
        const int o = c * CS;
        const float ctr = cp[o];
        float n;
        n = (vm2 && cv0) ? pr2[o - 2] : 0.f; a[0]  = fmaf(ctr, n, a[0]);
        n = (vm2 && cv1) ? pr2[o - 1] : 0.f; a[1]  = fmaf(ctr, n, a[1]);
        n =  vm2         ? pr2[o    ] : 0.f; a[2]  = fmaf(ctr, n, a[2]);
        n = (vm2 && cv3) ? pr2[o + 1] : 0.f; a[3]  = fmaf(ctr, n, a[3]);
        n = (vm2 && cv4) ? pr2[o + 2] : 0.f; a[4]  = fmaf(ctr, n, a[4]);
        n = (vm1 && cv0) ? pr1[o - 2] : 0.f; a[5]  = fmaf(ctr, n, a[5]);
        n = (vm1 && cv1) ? pr1[o - 1] : 0.f; a[6]  = fmaf(ctr, n, a[6]);
        n =  vm1         ? pr1[o    ] : 0.f; a[7]  = fmaf(ctr, n, a[7]);
        n = (vm1 && cv3) ? pr1[o + 1] : 0.f; a[8]  = fmaf(ctr, n, a[8]);
        n = (vm1 && cv4) ? pr1[o + 2] : 0.f; a[9]  = fmaf(ctr, n, a[9]);
        n =  cv0         ? cp [o - 2] : 0.f; a[10] = fmaf(ctr, n, a[10]);
        n =  cv1         ? cp [o - 1] : 0.f; a[11] = fmaf(ctr, n, a[11]);
        a[12] = fmaf(ctr, ctr, a[12]);
    }

    __shared__ float part[32][13][16];             // 26.6 KB
    #pragma unroll
    for (int i = 0; i < 13; ++i) part[ck][i][px] = a[i];
    __syncthreads();

    if (threadIdx.x < 13 * 16) {
        const int acc = threadIdx.x >> 4, pp = threadIdx.x & 15;
        float s = 0.f;
        #pragma unroll
        for (int j = 0; j < 32; ++j) s += part[j][acc][pp];
        dot[((size_t)(b * 13 + acc)) * PX + blockIdx.x * 16 + pp] = s;
    }
}

// Fused weights + output. block 512 = 16 px x 32 ch-subgroups (8 ch each).
// grid (196, 4). Phase 1: 400 (px,k) items -> sims, rank/top-10/exp, denom.
// Phase 2: per-thread 8 channels x 25 taps weighted accumulation.
__global__ __launch_bounds__(512) void k_fused(const float* __restrict__ x,
                                               const float* __restrict__ dot,
                                               const float* __restrict__ gptr,
                                               float* __restrict__ out) {
    const int tid   = threadIdx.x;
    const int pbase = blockIdx.x * 16;
    const int b     = blockIdx.y;
    const float* db = dot + (size_t)b * 13 * PX;

    __shared__ float s_lds[16][25];
    __shared__ float e_lds[16][25];
    __shared__ float inv_lds[16];

    // ---- phase 1a: sims into LDS (400 items, one per thread) ----
    if (tid < 400) {
        const int px = tid / 25, k = tid - px * 25;
        const int p = pbase + px;
        const int h = p / 56, w = p - (p / 56) * 56;
        const int dy = k / 5 - 2, dx = k % 5 - 2;
        const int rr = h + dy, cc = w + dx;
        const bool v = (rr >= 0) && (rr < 56) && (cc >= 0) && (cc < 56);
        float d = 0.f, n2 = 0.f;
        if (v) {
            const int q = rr * 56 + cc;
            n2 = db[12 * PX + q];
            d  = (k <= 12) ? db[k * PX + p] : db[(24 - k) * PX + q];
        }
        const float cn = sqrtf(db[12 * PX + p]);
        s_lds[px][k] = d / fmaxf(sqrtf(n2) * cn, 1e-8f) * 10.f;
    }
    __syncthreads();

    // ---- phase 1b: rank (exact top-10, JAX tie-break) + max + exp ----
    if (tid < 400) {
        const int px = tid / 25, k = tid - px * 25;
        const float sk = s_lds[px][k];
        int rank = 0;
        float m = sk;
        #pragma unroll
        for (int j = 0; j < 25; ++j) {
            const float sj = s_lds[px][j];
            rank += (int)((sj > sk) || ((sj == sk) && (j < k)));
            m = fmaxf(m, sj);
        }
        e_lds[px][k] = (rank < 10) ? __expf(sk - m) : 0.f;
    }
    __syncthreads();

    // ---- phase 1c: per-pixel denom ----
    if (tid < 16) {
        float denom = 0.f;
        #pragma unroll
        for (int k = 0; k < 25; ++k) denom += e_lds[tid][k];
        inv_lds[tid] = 1.f / denom;
    }
    __syncthreads();

    // ---- phase 2: weighted accumulation over channels ----
    const int px  = tid & 15;
    const int sub = tid >> 4;                      // 0..31, 8 channels each
    const int p   = pbase + px;
    const int h   = p / 56;
    const int w   = p - h * 56;
    const float g = *gptr;

    const float inv = inv_lds[px];
    float wk[25];
    #pragma unroll
    for (int k = 0; k < 25; ++k) wk[k] = e_lds[px][k] * inv;

    const float* xb = x   + ((size_t)b * 256 + sub * 8) * CS;
    float*       ob = out + ((size_t)b * 256 + sub * 8) * CS;

    #pragma unroll 2
    for (int ci = 0; ci < 8; ++ci) {
        const float* xp = xb + ci * CS;
        float y = 0.f;
        #pragma unroll
        for (int k = 0; k < 25; ++k) {
            const int dy = k / 5 - 2, dx = k % 5 - 2;
            const int rr = h + dy, cc = w + dx;
            const bool v = (rr >= 0) && (rr < 56) && (cc >= 0) && (cc < 56);
            const float xv = v ? xp[p + dy * 56 + dx] : 0.f;
            y = fmaf(wk[k], xv, y);
        }
        ob[ci * CS + p] = xp[p] + g * y;
    }
}

extern "C" void kernel_launch(void* const* d_in, const int* in_sizes, int n_in,
                              void* d_out, int out_size, void* d_ws, size_t ws_size,
                              hipStream_t stream) {
    const float* x     = (const float*)d_in[0];
    const float* gamma = (const float*)d_in[1];
    float* out = (float*)d_out;

    float* dot = (float*)d_ws;                 // [4][13][3136]

    k_dot<<<dim3(196, 4), 512, 0, stream>>>(x, dot);
    k_fused<<<dim3(196, 4), 512, 0, stream>>>(x, dot, gamma, out);
}

// Round 6
// 44.721 us; speedup vs baseline: 1.1120x; 1.1120x over previous
//
#include <hip/hip_runtime.h>
#include <hip/hip_bf16.h>

// LocalPPM: B=4, C=256, H=W=56, R=2 (5x5 -> K2=25), TOPK=10, TAU=0.1, EPS=1e-8
// out = x + gamma * sum_k softmax_top10(cos_sim(center, neighbor_k)/TAU) * neighbor_k
//
// Symmetry: dot(p, +o) == dot(p+o, -o); only 13 offsets k=0..12 computed
// (dy=-2,-1 full rows; dy=0, dx<=0); k_fused mirrors the rest.
//
// Grid shape: 32-px tiles (128B coalescing) x 32 channel-chunks (8 ch) =
// 1024 thr/block, 392 blocks, 6272 waves (6.1/SIMD) for both kernels.

#define PX 3136   // 56*56
#define CS 3136   // channel plane stride (H*W)

__global__ __launch_bounds__(1024) void k_dot(const float* __restrict__ x,
                                              float* __restrict__ dot) {
    const int px = threadIdx.x & 31;
    const int ck = threadIdx.x >> 5;               // 0..31 channel chunk (8 ch)
    const int p  = blockIdx.x * 32 + px;
    const int b  = blockIdx.y;
    const int h  = p / 56;
    const int w  = p - h * 56;

    const bool vm2 = (h >= 2), vm1 = (h >= 1);
    const bool cv0 = (w >= 2), cv1 = (w >= 1), cv3 = (w <= 54), cv4 = (w <= 53);

    const float* xb  = x + (size_t)b * 256 * CS + (size_t)ck * 8 * CS;
    const float* cp  = xb + p;        // center (row h, col w)
    const float* pr2 = cp - 112;      // row h-2
    const float* pr1 = cp - 56;       // row h-1

    float a[13];
    #pragma unroll
    for (int i = 0; i < 13; ++i) a[i] = 0.f;

    #pragma unroll
    for (int c = 0; c < 8; ++c) {
        const int o = c * CS;
        const float ctr = cp[o];
        float n;
        n = (vm2 && cv0) ? pr2[o - 2] : 0.f; a[0]  = fmaf(ctr, n, a[0]);
        n = (vm2 && cv1) ? pr2[o - 1] : 0.f; a[1]  = fmaf(ctr, n, a[1]);
        n =  vm2         ? pr2[o    ] : 0.f; a[2]  = fmaf(ctr, n, a[2]);
        n = (vm2 && cv3) ? pr2[o + 1] : 0.f; a[3]  = fmaf(ctr, n, a[3]);
        n = (vm2 && cv4) ? pr2[o + 2] : 0.f; a[4]  = fmaf(ctr, n, a[4]);
        n = (vm1 && cv0) ? pr1[o - 2] : 0.f; a[5]  = fmaf(ctr, n, a[5]);
        n = (vm1 && cv1) ? pr1[o - 1] : 0.f; a[6]  = fmaf(ctr, n, a[6]);
        n =  vm1         ? pr1[o    ] : 0.f; a[7]  = fmaf(ctr, n, a[7]);
        n = (vm1 && cv3) ? pr1[o + 1] : 0.f; a[8]  = fmaf(ctr, n, a[8]);
        n = (vm1 && cv4) ? pr1[o + 2] : 0.f; a[9]  = fmaf(ctr, n, a[9]);
        n =  cv0         ? cp [o - 2] : 0.f; a[10] = fmaf(ctr, n, a[10]);
        n =  cv1         ? cp [o - 1] : 0.f; a[11] = fmaf(ctr, n, a[11]);
        a[12] = fmaf(ctr, ctr, a[12]);
    }

    __shared__ float part[32][13][32];             // 53.2 KB
    #pragma unroll
    for (int i = 0; i < 13; ++i) part[ck][i][px] = a[i];
    __syncthreads();

    if (threadIdx.x < 13 * 32) {
        const int acc = threadIdx.x >> 5, pp = threadIdx.x & 31;
        float s = 0.f;
        #pragma unroll
        for (int j = 0; j < 32; ++j) s += part[j][acc][pp];
        dot[((size_t)(b * 13 + acc)) * PX + blockIdx.x * 32 + pp] = s;
    }
}

// Fused weights + output. block 1024 = 32 px x 32 ch-subgroups (8 ch each).
// grid (98, 4). Phase 1: 800 (px,k) items single-shot -> sims, rank, exp.
// Phase 2: per-thread 8 channels x 25 taps weighted accumulation.
__global__ __launch_bounds__(1024) void k_fused(const float* __restrict__ x,
                                                const float* __restrict__ dot,
                                                const float* __restrict__ gptr,
                                                float* __restrict__ out) {
    const int tid   = threadIdx.x;
    const int pbase = blockIdx.x * 32;
    const int b     = blockIdx.y;
    const float* db = dot + (size_t)b * 13 * PX;

    __shared__ float s_lds[32][25];
    __shared__ float e_lds[32][25];
    __shared__ float inv_lds[32];

    // ---- phase 1a: sims into LDS (800 items, one per thread) ----
    if (tid < 800) {
        const int px = tid / 25, k = tid - (tid / 25) * 25;
        const int p = pbase + px;
        const int h = p / 56, w = p - (p / 56) * 56;
        const int dy = k / 5 - 2, dx = k % 5 - 2;
        const int rr = h + dy, cc = w + dx;
        const bool v = (rr >= 0) && (rr < 56) && (cc >= 0) && (cc < 56);
        float d = 0.f, n2 = 0.f;
        if (v) {
            const int q = rr * 56 + cc;
            n2 = db[12 * PX + q];
            d  = (k <= 12) ? db[k * PX + p] : db[(24 - k) * PX + q];
        }
        const float cn = sqrtf(db[12 * PX + p]);
        s_lds[px][k] = d / fmaxf(sqrtf(n2) * cn, 1e-8f) * 10.f;
    }
    __syncthreads();

    // ---- phase 1b: rank (exact top-10, JAX tie-break) + max + exp ----
    if (tid < 800) {
        const int px = tid / 25, k = tid - (tid / 25) * 25;
        const float sk = s_lds[px][k];
        int rank = 0;
        float m = sk;
        #pragma unroll
        for (int j = 0; j < 25; ++j) {
            const float sj = s_lds[px][j];
            rank += (int)((sj > sk) || ((sj == sk) && (j < k)));
            m = fmaxf(m, sj);
        }
        e_lds[px][k] = (rank < 10) ? __expf(sk - m) : 0.f;
    }
    __syncthreads();

    // ---- phase 1c: per-pixel denom ----
    if (tid < 32) {
        float denom = 0.f;
        #pragma unroll
        for (int k = 0; k < 25; ++k) denom += e_lds[tid][k];
        inv_lds[tid] = 1.f / denom;
    }
    __syncthreads();

    // ---- phase 2: weighted accumulation over channels ----
    const int px  = tid & 31;
    const int sub = tid >> 5;                      // 0..31, 8 channels each
    const int p   = pbase + px;
    const int h   = p / 56;
    const int w   = p - h * 56;
    const float g = *gptr;

    const float inv = inv_lds[px];
    float wk[25];
    #pragma unroll
    for (int k = 0; k < 25; ++k) wk[k] = e_lds[px][k] * inv;

    const float* xb = x   + ((size_t)b * 256 + sub * 8) * CS;
    float*       ob = out + ((size_t)b * 256 + sub * 8) * CS;

    #pragma unroll 2
    for (int ci = 0; ci < 8; ++ci) {
        const float* xp = xb + ci * CS;
        float y = 0.f;
        #pragma unroll
        for (int k = 0; k < 25; ++k) {
            const int dy = k / 5 - 2, dx = k % 5 - 2;
            const int rr = h + dy, cc = w + dx;
            const bool v = (rr >= 0) && (rr < 56) && (cc >= 0) && (cc < 56);
            const float xv = v ? xp[p + dy * 56 + dx] : 0.f;
            y = fmaf(wk[k], xv, y);
        }
        ob[ci * CS + p] = xp[p] + g * y;
    }
}

extern "C" void kernel_launch(void* const* d_in, const int* in_sizes, int n_in,
                              void* d_out, int out_size, void* d_ws, size_t ws_size,
                              hipStream_t stream) {
    const float* x     = (const float*)d_in[0];
    const float* gamma = (const float*)d_in[1];
    float* out = (float*)d_out;

    float* dot = (float*)d_ws;                 // [4][13][3136]

    k_dot<<<dim3(98, 4), 1024, 0, stream>>>(x, dot);
    k_fused<<<dim3(98, 4), 1024, 0, stream>>>(x, dot, gamma, out);
}

// Round 7
// 40.274 us; speedup vs baseline: 1.2348x; 1.1104x over previous
//
#include <hip/hip_runtime.h>
#include <hip/hip_bf16.h>

// LocalPPM: B=4, C=256, H=W=56, R=2 (5x5 -> K2=25), TOPK=10, TAU=0.1, EPS=1e-8
// out = x + gamma * sum_k softmax_top10(cos_sim(center, neighbor_k)/TAU) * neighbor_k
//
// Symmetry: dot(p, +o) == dot(p+o, -o); only 13 offsets k=0..12 computed.
// This round: tap loads are UNCONDITIONAL dwordx4/dword vector loads +
// v_cndmask on components (no exec-masked loads). Edge channels (global ch 0
// start / ch 1023 end) peel to the masked-scalar path for memory safety;
// all other cross-plane reads are in-bounds garbage that masking zeroes.

#define PX 3136   // 56*56
#define CS 3136   // channel plane stride (H*W)

typedef float f4a __attribute__((ext_vector_type(4), aligned(4)));
typedef float f2a __attribute__((ext_vector_type(2), aligned(4)));

// block 512 = 32 px x 16 ch-chunks (16 ch each); grid (98, 4).
__global__ __launch_bounds__(512) void k_dot(const float* __restrict__ x,
                                             float* __restrict__ dot) {
    const int px = threadIdx.x & 31;
    const int ck = threadIdx.x >> 5;               // 0..15 channel chunk (16 ch)
    const int p  = blockIdx.x * 32 + px;
    const int b  = blockIdx.y;
    const int h  = p / 56;
    const int w  = p - h * 56;

    const bool vm2 = (h >= 2), vm1 = (h >= 1);
    const bool cv0 = (w >= 2), cv1 = (w >= 1), cv3 = (w <= 54), cv4 = (w <= 53);

    const float* xb  = x + (size_t)b * 256 * CS + (size_t)ck * 16 * CS;
    const float* cp  = xb + p;        // center (row h, col w)
    const float* pr2 = cp - 112;      // row h-2
    const float* pr1 = cp - 56;       // row h-1

    float a[13];
    #pragma unroll
    for (int i = 0; i < 13; ++i) a[i] = 0.f;

    // c == 0: exec-masked scalar path (memory-safe at tensor boundaries)
    {
        const float ctr = cp[0];
        float n;
        n = (vm2 && cv0) ? pr2[-2] : 0.f; a[0]  = fmaf(ctr, n, a[0]);
        n = (vm2 && cv1) ? pr2[-1] : 0.f; a[1]  = fmaf(ctr, n, a[1]);
        n =  vm2         ? pr2[ 0] : 0.f; a[2]  = fmaf(ctr, n, a[2]);
        n = (vm2 && cv3) ? pr2[ 1] : 0.f; a[3]  = fmaf(ctr, n, a[3]);
        n = (vm2 && cv4) ? pr2[ 2] : 0.f; a[4]  = fmaf(ctr, n, a[4]);
        n = (vm1 && cv0) ? pr1[-2] : 0.f; a[5]  = fmaf(ctr, n, a[5]);
        n = (vm1 && cv1) ? pr1[-1] : 0.f; a[6]  = fmaf(ctr, n, a[6]);
        n =  vm1         ? pr1[ 0] : 0.f; a[7]  = fmaf(ctr, n, a[7]);
        n = (vm1 && cv3) ? pr1[ 1] : 0.f; a[8]  = fmaf(ctr, n, a[8]);
        n = (vm1 && cv4) ? pr1[ 2] : 0.f; a[9]  = fmaf(ctr, n, a[9]);
        n =  cv0         ? cp [-2] : 0.f; a[10] = fmaf(ctr, n, a[10]);
        n =  cv1         ? cp [-1] : 0.f; a[11] = fmaf(ctr, n, a[11]);
        a[12] = fmaf(ctr, ctr, a[12]);
    }

    // c = 1..15: unconditional vector loads + cndmask (always in-bounds)
    #pragma unroll 5
    for (int c = 1; c < 16; ++c) {
        const int o = c * CS;
        const f4a   t2  = *(const f4a*)(pr2 + o - 2);   // row h-2, dx -2..+1
        const float t2e = pr2[o + 2];                   // dx +2
        const f4a   t1  = *(const f4a*)(pr1 + o - 2);   // row h-1
        const float t1e = pr1[o + 2];
        const f2a   t0  = *(const f2a*)(cp + o - 2);    // row h, dx -2,-1
        const float ctr = cp[o];
        a[0]  = fmaf(ctr, (vm2 && cv0) ? t2.x : 0.f, a[0]);
        a[1]  = fmaf(ctr, (vm2 && cv1) ? t2.y : 0.f, a[1]);
        a[2]  = fmaf(ctr,  vm2         ? t2.z : 0.f, a[2]);
        a[3]  = fmaf(ctr, (vm2 && cv3) ? t2.w : 0.f, a[3]);
        a[4]  = fmaf(ctr, (vm2 && cv4) ? t2e  : 0.f, a[4]);
        a[5]  = fmaf(ctr, (vm1 && cv0) ? t1.x : 0.f, a[5]);
        a[6]  = fmaf(ctr, (vm1 && cv1) ? t1.y : 0.f, a[6]);
        a[7]  = fmaf(ctr,  vm1         ? t1.z : 0.f, a[7]);
        a[8]  = fmaf(ctr, (vm1 && cv3) ? t1.w : 0.f, a[8]);
        a[9]  = fmaf(ctr, (vm1 && cv4) ? t1e  : 0.f, a[9]);
        a[10] = fmaf(ctr,  cv0         ? t0.x : 0.f, a[10]);
        a[11] = fmaf(ctr,  cv1         ? t0.y : 0.f, a[11]);
        a[12] = fmaf(ctr, ctr, a[12]);
    }

    __shared__ float part[16][13][32];             // 26.6 KB
    #pragma unroll
    for (int i = 0; i < 13; ++i) part[ck][i][px] = a[i];
    __syncthreads();

    if (threadIdx.x < 13 * 32) {
        const int acc = threadIdx.x >> 5, pp = threadIdx.x & 31;
        float s = 0.f;
        #pragma unroll
        for (int j = 0; j < 16; ++j) s += part[j][acc][pp];
        dot[((size_t)(b * 13 + acc)) * PX + blockIdx.x * 32 + pp] = s;
    }
}

// 25-tap weighted gather for one channel. vecsafe=false only at the two
// tensor-corner channels (global ch 0 / ch 1023).
__device__ __forceinline__ float tap25(const float* __restrict__ xp,
                                       const float* __restrict__ wk,
                                       bool vecsafe, float& ctr_out,
                                       bool vm2, bool vm1, bool vp1, bool vp2,
                                       bool cv0, bool cv1, bool cv3, bool cv4) {
    float y = 0.f;
    if (vecsafe) {
        #pragma unroll
        for (int r = 0; r < 5; ++r) {
            const bool vr = (r == 0) ? vm2 : (r == 1) ? vm1 : (r == 2) ? true
                          : (r == 3) ? vp1 : vp2;
            const float* rp = xp + (r - 2) * 56;
            const f4a   v4 = *(const f4a*)(rp - 2);    // dx -2..+1
            const float s4 = rp[2];                    // dx +2
            if (r == 2) ctr_out = v4.z;
            y = fmaf(wk[r*5+0], (vr && cv0) ? v4.x : 0.f, y);
            y = fmaf(wk[r*5+1], (vr && cv1) ? v4.y : 0.f, y);
            y = fmaf(wk[r*5+2],  vr         ? v4.z : 0.f, y);
            y = fmaf(wk[r*5+3], (vr && cv3) ? v4.w : 0.f, y);
            y = fmaf(wk[r*5+4], (vr && cv4) ? s4   : 0.f, y);
        }
    } else {
        ctr_out = xp[0];
        #pragma unroll
        for (int k = 0; k < 25; ++k) {
            const int dy = k / 5 - 2, dx = k % 5 - 2;
            const bool vr = (dy == -2) ? vm2 : (dy == -1) ? vm1 : (dy == 0) ? true
                          : (dy == 1) ? vp1 : vp2;
            const bool vc = (dx == -2) ? cv0 : (dx == -1) ? cv1 : (dx == 0) ? true
                          : (dx == 1) ? cv3 : cv4;
            const float xv = (vr && vc) ? xp[dy * 56 + dx] : 0.f;
            y = fmaf(wk[k], xv, y);
        }
    }
    return y;
}

// Fused weights + output. block 512 = 32 px x 16 ch-subgroups (16 ch each).
// grid (98, 4).
__global__ __launch_bounds__(512) void k_fused(const float* __restrict__ x,
                                               const float* __restrict__ dot,
                                               const float* __restrict__ gptr,
                                               float* __restrict__ out) {
    const int tid   = threadIdx.x;
    const int pbase = blockIdx.x * 32;
    const int b     = blockIdx.y;
    const float* db = dot + (size_t)b * 13 * PX;

    __shared__ float s_lds[32][25];
    __shared__ float e_lds[32][25];
    __shared__ float inv_lds[32];

    // ---- phase 1a: sims into LDS ----
    #pragma unroll
    for (int i = tid; i < 800; i += 512) {
        const int px = i / 25, k = i - px * 25;
        const int p = pbase + px;
        const int h = p / 56, w = p - (p / 56) * 56;
        const int dy = k / 5 - 2, dx = k % 5 - 2;
        const int rr = h + dy, cc = w + dx;
        const bool v = (rr >= 0) && (rr < 56) && (cc >= 0) && (cc < 56);
        float d = 0.f, n2 = 0.f;
        if (v) {
            const int q = rr * 56 + cc;
            n2 = db[12 * PX + q];
            d  = (k <= 12) ? db[k * PX + p] : db[(24 - k) * PX + q];
        }
        const float cn = sqrtf(db[12 * PX + p]);
        s_lds[px][k] = d / fmaxf(sqrtf(n2) * cn, 1e-8f) * 10.f;
    }
    __syncthreads();

    // ---- phase 1b: rank (exact top-10, JAX tie-break) + max + exp ----
    #pragma unroll
    for (int i = tid; i < 800; i += 512) {
        const int px = i / 25, k = i - px * 25;
        const float sk = s_lds[px][k];
        int rank = 0;
        float m = sk;
        #pragma unroll
        for (int j = 0; j < 25; ++j) {
            const float sj = s_lds[px][j];
            rank += (int)((sj > sk) || ((sj == sk) && (j < k)));
            m = fmaxf(m, sj);
        }
        e_lds[px][k] = (rank < 10) ? __expf(sk - m) : 0.f;
    }
    __syncthreads();

    // ---- phase 1c: per-pixel denom ----
    if (tid < 32) {
        float denom = 0.f;
        #pragma unroll
        for (int k = 0; k < 25; ++k) denom += e_lds[tid][k];
        inv_lds[tid] = 1.f / denom;
    }
    __syncthreads();

    // ---- phase 2: weighted accumulation over channels ----
    const int px  = tid & 31;
    const int sub = tid >> 5;                      // 0..15, 16 channels each
    const int p   = pbase + px;
    const int h   = p / 56;
    const int w   = p - h * 56;
    const float g = *gptr;

    const bool vm2 = (h >= 2), vm1 = (h >= 1), vp1 = (h <= 54), vp2 = (h <= 53);
    const bool cv0 = (w >= 2), cv1 = (w >= 1), cv3 = (w <= 54), cv4 = (w <= 53);

    const float inv = inv_lds[px];
    float wk[25];
    #pragma unroll
    for (int k = 0; k < 25; ++k) wk[k] = e_lds[px][k] * inv;

    const float* xb = x   + ((size_t)b * 256 + sub * 16) * CS;
    float*       ob = out + ((size_t)b * 256 + sub * 16) * CS;

    #pragma unroll 2
    for (int ci = 0; ci < 16; ++ci) {
        const bool vecsafe = !((b == 0 && sub == 0 && ci == 0) ||
                               (b == 3 && sub == 15 && ci == 15));
        float ctr;
        const float y = tap25(xb + ci * CS + p, wk, vecsafe, ctr,
                              vm2, vm1, vp1, vp2, cv0, cv1, cv3, cv4);
        ob[ci * CS + p] = ctr + g * y;
    }
}

extern "C" void kernel_launch(void* const* d_in, const int* in_sizes, int n_in,
                              void* d_out, int out_size, void* d_ws, size_t ws_size,
                              hipStream_t stream) {
    const float* x     = (const float*)d_in[0];
    const float* gamma = (const float*)d_in[1];
    float* out = (float*)d_out;

    float* dot = (float*)d_ws;                 // [4][13][3136]

    k_dot<<<dim3(98, 4), 512, 0, stream>>>(x, dot);
    k_fused<<<dim3(98, 4), 512, 0, stream>>>(x, dot, gamma, out);
}